// Round 1
// baseline (3387.372 us; speedup 1.0000x reference)
//
#include <hip/hip_runtime.h>
#include <hip/hip_bf16.h>

#define HID 128
#define IN_DIM 16

// ---------------- degree / dinv ----------------
__global__ __launch_bounds__(256) void k_deg_init(float* deg, int N) {
    int i = blockIdx.x * blockDim.x + threadIdx.x;
    if (i < N) deg[i] = 1.0f;  // self loop
}

__global__ __launch_bounds__(256) void k_deg_edges(const int* __restrict__ dst, float* deg, int E) {
    int e = blockIdx.x * blockDim.x + threadIdx.x;
    if (e < E) atomicAdd(&deg[dst[e]], 1.0f);
}

__global__ __launch_bounds__(256) void k_dinv(float* deg, int N) {
    int i = blockIdx.x * blockDim.x + threadIdx.x;
    if (i < N) deg[i] = rsqrtf(deg[i]);   // deg >= 1 always
}

// ---------------- zero helpers ----------------
__global__ __launch_bounds__(256) void k_zero4(float* p, int n4) {  // n4 = count of float4
    int i = blockIdx.x * blockDim.x + threadIdx.x;
    if (i < n4) reinterpret_cast<float4*>(p)[i] = make_float4(0.f, 0.f, 0.f, 0.f);
}

__global__ __launch_bounds__(256) void k_zero1(float* p, int n) {
    int i = blockIdx.x * blockDim.x + threadIdx.x;
    if (i < n) p[i] = 0.f;
}

// ---------------- counts per graph ----------------
__global__ __launch_bounds__(256) void k_cnt(const int* __restrict__ batch, float* cnt, int N) {
    int i = blockIdx.x * blockDim.x + threadIdx.x;
    if (i < N) atomicAdd(&cnt[batch[i]], 1.0f);
}

// ---------------- GEMM1: out[i] = dinv[i] * (x[i] @ W1), x [N,16], W1 [16,128] ----------------
__global__ __launch_bounds__(256) void k_gemm1(const float* __restrict__ x,
                                               const float* __restrict__ W1,
                                               const float* __restrict__ dinv,
                                               float* __restrict__ out, int N) {
    __shared__ float Ws[IN_DIM * HID];   // 8 KB
    __shared__ float xs[8][IN_DIM];      // 512 B
    int nb = blockIdx.x * 8;
    for (int i = threadIdx.x * 4; i < IN_DIM * HID; i += 256 * 4)
        *reinterpret_cast<float4*>(&Ws[i]) = *reinterpret_cast<const float4*>(&W1[i]);
    int nrows = min(8, N - nb);
    if (threadIdx.x < 32) {   // 8 rows * 16 floats = 128 floats = 32 float4
        int r = threadIdx.x >> 2, c = (threadIdx.x & 3) * 4;
        if (r < nrows)
            *reinterpret_cast<float4*>(&xs[r][c]) =
                *reinterpret_cast<const float4*>(&x[(size_t)(nb + r) * IN_DIM + c]);
    }
    __syncthreads();
    int f = threadIdx.x & 127;
    int g = threadIdx.x >> 7;  // 0..1
    for (int r = g; r < nrows; r += 2) {
        int node = nb + r;
        float acc = 0.f;
        #pragma unroll
        for (int k = 0; k < IN_DIM; ++k) acc += xs[r][k] * Ws[k * HID + f];
        out[(size_t)node * HID + f] = dinv[node] * acc;
    }
}

// ---------------- edge scatter: agg[dst] += h[src] (32 threads/edge, float4) ----------------
__global__ __launch_bounds__(256) void k_scatter(const float* __restrict__ h,
                                                 float* __restrict__ agg,
                                                 const int* __restrict__ src,
                                                 const int* __restrict__ dst, int E) {
    int t = blockIdx.x * blockDim.x + threadIdx.x;
    int e = t >> 5;
    if (e >= E) return;
    int c = (t & 31) << 2;
    int s = src[e], d = dst[e];
    float4 v = *reinterpret_cast<const float4*>(h + (size_t)s * HID + c);
    float* p = agg + (size_t)d * HID + c;
    atomicAdd(p + 0, v.x);
    atomicAdd(p + 1, v.y);
    atomicAdd(p + 2, v.z);
    atomicAdd(p + 3, v.w);
}

// ---------------- epilogue 1: h = relu(dinv*(agg + h) + b)  (in-place on h) ----------------
__global__ __launch_bounds__(256) void k_epi1(float* __restrict__ h,
                                              const float* __restrict__ agg,
                                              const float* __restrict__ dinv,
                                              const float* __restrict__ bias, int N) {
    int t = blockIdx.x * blockDim.x + threadIdx.x;
    int total = N * (HID / 4);
    if (t >= total) return;
    int i = t >> 5, c = (t & 31) * 4;
    float di = dinv[i];
    float4 a = *reinterpret_cast<const float4*>(h + (size_t)i * HID + c);
    float4 g = *reinterpret_cast<const float4*>(agg + (size_t)i * HID + c);
    float4 bb = *reinterpret_cast<const float4*>(bias + c);
    float4 o;
    o.x = fmaxf(di * (a.x + g.x) + bb.x, 0.f);
    o.y = fmaxf(di * (a.y + g.y) + bb.y, 0.f);
    o.z = fmaxf(di * (a.z + g.z) + bb.z, 0.f);
    o.w = fmaxf(di * (a.w + g.w) + bb.w, 0.f);
    *reinterpret_cast<float4*>(h + (size_t)i * HID + c) = o;
}

// ---------------- GEMM2 (in-place): h[i] = dinv[i] * (h[i] @ W2), W2 [128,128] ----------------
__global__ __launch_bounds__(128) void k_gemm2(float* __restrict__ hbuf,
                                               const float* __restrict__ W2,
                                               const float* __restrict__ dinv, int N) {
    __shared__ float Ws[HID * HID];   // 64 KB
    __shared__ float xs[16][HID];     // 8 KB
    int nb = blockIdx.x * 16;
    for (int i = threadIdx.x * 4; i < HID * HID; i += 128 * 4)
        *reinterpret_cast<float4*>(&Ws[i]) = *reinterpret_cast<const float4*>(&W2[i]);
    int nrows = min(16, N - nb);
    for (int i = threadIdx.x * 4; i < nrows * HID; i += 128 * 4) {
        int r = i >> 7, c = i & 127;
        *reinterpret_cast<float4*>(&xs[r][c]) =
            *reinterpret_cast<const float4*>(&hbuf[(size_t)(nb + r) * HID + c]);
    }
    __syncthreads();
    int f4 = (threadIdx.x & 31) * 4;
    int ng = threadIdx.x >> 5;   // 0..3 -> nodes ng*4 .. ng*4+3
    float acc[4][4] = {};
    for (int k = 0; k < HID; ++k) {
        float4 w = *reinterpret_cast<const float4*>(&Ws[k * HID + f4]);
        #pragma unroll
        for (int r = 0; r < 4; ++r) {
            float xv = xs[ng * 4 + r][k];
            acc[r][0] += xv * w.x;
            acc[r][1] += xv * w.y;
            acc[r][2] += xv * w.z;
            acc[r][3] += xv * w.w;
        }
    }
    #pragma unroll
    for (int r = 0; r < 4; ++r) {
        int node = nb + ng * 4 + r;
        if (node >= N) break;
        float di = dinv[node];
        float4 o = make_float4(di * acc[r][0], di * acc[r][1], di * acc[r][2], di * acc[r][3]);
        *reinterpret_cast<float4*>(&hbuf[(size_t)node * HID + f4]) = o;
    }
}

// ---------------- epilogue 2 + pooling: pooled[batch[i]] += relu(dinv*(agg+h)+b) ----------------
__global__ __launch_bounds__(256) void k_epi2_pool(const float* __restrict__ h,
                                                   const float* __restrict__ agg,
                                                   const float* __restrict__ dinv,
                                                   const float* __restrict__ bias,
                                                   const int* __restrict__ batch,
                                                   float* __restrict__ pooled, int N) {
    int t = blockIdx.x * blockDim.x + threadIdx.x;
    int total = N * (HID / 4);
    if (t >= total) return;
    int i = t >> 5, c = (t & 31) * 4;
    float di = dinv[i];
    float4 a = *reinterpret_cast<const float4*>(h + (size_t)i * HID + c);
    float4 g = *reinterpret_cast<const float4*>(agg + (size_t)i * HID + c);
    float4 bb = *reinterpret_cast<const float4*>(bias + c);
    float vx = fmaxf(di * (a.x + g.x) + bb.x, 0.f);
    float vy = fmaxf(di * (a.y + g.y) + bb.y, 0.f);
    float vz = fmaxf(di * (a.z + g.z) + bb.z, 0.f);
    float vw = fmaxf(di * (a.w + g.w) + bb.w, 0.f);
    float* p = pooled + (size_t)batch[i] * HID + c;
    atomicAdd(p + 0, vx);
    atomicAdd(p + 1, vy);
    atomicAdd(p + 2, vz);
    atomicAdd(p + 3, vw);
}

// ---------------- final FC: out[g][o] = dot(pooled[g], Wfc[:,o]) / cnt[g] + bfc[o] ----------------
__global__ __launch_bounds__(256) void k_fc(const float* __restrict__ pooled,
                                            const float* __restrict__ cnt,
                                            const float* __restrict__ Wfc,
                                            const float* __restrict__ bfc,
                                            float* __restrict__ out, int G, int O) {
    int t = blockIdx.x * blockDim.x + threadIdx.x;
    if (t >= G * O) return;
    int g = t / O, o = t % O;
    float acc = 0.f;
    for (int k = 0; k < HID; ++k) acc += pooled[(size_t)g * HID + k] * Wfc[(size_t)k * O + o];
    out[t] = acc / fmaxf(cnt[g], 1.f) + bfc[o];
}

extern "C" void kernel_launch(void* const* d_in, const int* in_sizes, int n_in,
                              void* d_out, int out_size, void* d_ws, size_t ws_size,
                              hipStream_t stream) {
    const float* x    = (const float*)d_in[0];
    const int*   ei   = (const int*)d_in[1];
    const int*   batch = (const int*)d_in[2];
    const float* W1   = (const float*)d_in[3];
    const float* b1   = (const float*)d_in[4];
    const float* W2   = (const float*)d_in[5];
    const float* b2   = (const float*)d_in[6];
    const float* Wfc  = (const float*)d_in[7];
    const float* bfc  = (const float*)d_in[8];
    float* out = (float*)d_out;

    const int E = in_sizes[1] / 2;
    const int N = in_sizes[2];
    const int O = in_sizes[8];              // 16
    const int G = out_size / O;             // 64

    const int* src = ei;
    const int* dst = ei + E;

    // workspace layout (floats)
    float* ws = (float*)d_ws;
    float* dinv   = ws;                       // N (doubles as deg)
    float* pooled = dinv + N;                 // G*HID
    float* cnt    = pooled + (size_t)G * HID; // G
    float* bufA   = cnt + G;                  // N*HID  (h')
    float* bufB   = bufA + (size_t)N * HID;   // N*HID  (agg)

    const int BS = 256;
    const int NH4 = N * (HID / 4);

    // deg / dinv
    k_deg_init<<<(N + BS - 1) / BS, BS, 0, stream>>>(dinv, N);
    k_deg_edges<<<(E + BS - 1) / BS, BS, 0, stream>>>(dst, dinv, E);
    k_dinv<<<(N + BS - 1) / BS, BS, 0, stream>>>(dinv, N);

    // zero pooled + cnt, count nodes per graph
    k_zero1<<<(G * HID + G + BS - 1) / BS, BS, 0, stream>>>(pooled, G * HID + G);
    k_cnt<<<(N + BS - 1) / BS, BS, 0, stream>>>(batch, cnt, N);

    // conv1
    k_gemm1<<<(N + 7) / 8, BS, 0, stream>>>(x, W1, dinv, bufA, N);
    k_zero4<<<(NH4 + BS - 1) / BS, BS, 0, stream>>>(bufB, NH4);
    {
        long long t = (long long)E * 32;
        k_scatter<<<(int)((t + BS - 1) / BS), BS, 0, stream>>>(bufA, bufB, src, dst, E);
    }
    k_epi1<<<(NH4 + BS - 1) / BS, BS, 0, stream>>>(bufA, bufB, dinv, b1, N);

    // conv2
    k_gemm2<<<(N + 15) / 16, 128, 0, stream>>>(bufA, W2, dinv, N);
    k_zero4<<<(NH4 + BS - 1) / BS, BS, 0, stream>>>(bufB, NH4);
    {
        long long t = (long long)E * 32;
        k_scatter<<<(int)((t + BS - 1) / BS), BS, 0, stream>>>(bufA, bufB, src, dst, E);
    }
    k_epi2_pool<<<(NH4 + BS - 1) / BS, BS, 0, stream>>>(bufA, bufB, dinv, b2, batch, pooled, N);

    // FC head
    k_fc<<<(G * O + BS - 1) / BS, BS, 0, stream>>>(pooled, cnt, Wfc, bfc, out, G, O);
}

// Round 2
// 722.839 us; speedup vs baseline: 4.6862x; 4.6862x over previous
//
#include <hip/hip_runtime.h>
#include <hip/hip_bf16.h>

#define HID 128
#define IN_DIM 16

// ---------------- CSR build: in-degree ----------------
__global__ __launch_bounds__(256) void k_indeg_zero(int* indeg, int N) {
    int i = blockIdx.x * blockDim.x + threadIdx.x;
    if (i < N) indeg[i] = 0;
}

__global__ __launch_bounds__(256) void k_count(const int* __restrict__ dst, int* indeg, int E) {
    int e = blockIdx.x * blockDim.x + threadIdx.x;
    if (e < E) atomicAdd(&indeg[dst[e]], 1);
}

__global__ __launch_bounds__(256) void k_dinv(const int* __restrict__ indeg, float* dinv, int N) {
    int i = blockIdx.x * blockDim.x + threadIdx.x;
    if (i < N) dinv[i] = rsqrtf(1.0f + (float)indeg[i]);   // self loop included
}

// ---------------- 2-level exclusive scan over indeg (1024 elems / block) ----------------
__global__ __launch_bounds__(256) void k_scan1(const int* __restrict__ indeg, int* __restrict__ offs,
                                               int* __restrict__ blocksum, int N) {
    __shared__ int sdata[256];
    int base = blockIdx.x * 1024 + threadIdx.x * 4;
    int v0 = (base + 0 < N) ? indeg[base + 0] : 0;
    int v1 = (base + 1 < N) ? indeg[base + 1] : 0;
    int v2 = (base + 2 < N) ? indeg[base + 2] : 0;
    int v3 = (base + 3 < N) ? indeg[base + 3] : 0;
    int s = v0 + v1 + v2 + v3;
    sdata[threadIdx.x] = s;
    __syncthreads();
    for (int off = 1; off < 256; off <<= 1) {
        int t = (threadIdx.x >= off) ? sdata[threadIdx.x - off] : 0;
        __syncthreads();
        sdata[threadIdx.x] += t;
        __syncthreads();
    }
    int excl = sdata[threadIdx.x] - s;
    if (base + 0 < N) offs[base + 0] = excl;  excl += v0;
    if (base + 1 < N) offs[base + 1] = excl;  excl += v1;
    if (base + 2 < N) offs[base + 2] = excl;  excl += v2;
    if (base + 3 < N) offs[base + 3] = excl;
    if (threadIdx.x == 255) blocksum[blockIdx.x] = sdata[255];
}

__global__ void k_scan2(int* blocksum, int nblk) {
    if (blockIdx.x == 0 && threadIdx.x == 0) {
        int acc = 0;
        for (int i = 0; i < nblk; ++i) { int t = blocksum[i]; blocksum[i] = acc; acc += t; }
    }
}

__global__ __launch_bounds__(256) void k_scan3(int* __restrict__ offs, int* __restrict__ cursor,
                                               const int* __restrict__ blocksum, int N) {
    int i = blockIdx.x * blockDim.x + threadIdx.x;
    if (i < N) {
        int o = offs[i] + blocksum[i >> 10];
        offs[i] = o;
        cursor[i] = o;
    }
}

__global__ __launch_bounds__(256) void k_fill(const int* __restrict__ src, const int* __restrict__ dst,
                                              int* __restrict__ cursor, int* __restrict__ csr, int E) {
    int e = blockIdx.x * blockDim.x + threadIdx.x;
    if (e < E) {
        int pos = atomicAdd(&cursor[dst[e]], 1);
        csr[pos] = src[e];
    }
}

// ---------------- zero helper ----------------
__global__ __launch_bounds__(256) void k_zero1(float* p, int n) {
    int i = blockIdx.x * blockDim.x + threadIdx.x;
    if (i < n) p[i] = 0.f;
}

// ---------------- counts per graph ----------------
__global__ __launch_bounds__(256) void k_cnt(const int* __restrict__ batch, float* cnt, int N) {
    int i = blockIdx.x * blockDim.x + threadIdx.x;
    if (i < N) atomicAdd(&cnt[batch[i]], 1.0f);
}

// ---------------- GEMM1: out[i] = dinv[i] * (x[i] @ W1), x [N,16], W1 [16,128] ----------------
__global__ __launch_bounds__(256) void k_gemm1(const float* __restrict__ x,
                                               const float* __restrict__ W1,
                                               const float* __restrict__ dinv,
                                               float* __restrict__ out, int N) {
    __shared__ float Ws[IN_DIM * HID];   // 8 KB
    __shared__ float xs[8][IN_DIM];      // 512 B
    int nb = blockIdx.x * 8;
    for (int i = threadIdx.x * 4; i < IN_DIM * HID; i += 256 * 4)
        *reinterpret_cast<float4*>(&Ws[i]) = *reinterpret_cast<const float4*>(&W1[i]);
    int nrows = min(8, N - nb);
    if (threadIdx.x < 32) {
        int r = threadIdx.x >> 2, c = (threadIdx.x & 3) * 4;
        if (r < nrows)
            *reinterpret_cast<float4*>(&xs[r][c]) =
                *reinterpret_cast<const float4*>(&x[(size_t)(nb + r) * IN_DIM + c]);
    }
    __syncthreads();
    int f = threadIdx.x & 127;
    int g = threadIdx.x >> 7;
    for (int r = g; r < nrows; r += 2) {
        int node = nb + r;
        float acc = 0.f;
        #pragma unroll
        for (int k = 0; k < IN_DIM; ++k) acc += xs[r][k] * Ws[k * HID + f];
        out[(size_t)node * HID + f] = dinv[node] * acc;
    }
}

// ---------------- gather helper: sum of neighbor rows (float4 slice) ----------------
__device__ __forceinline__ float4 gather_sum(const float* __restrict__ h,
                                             const int* __restrict__ csr,
                                             int base, int deg, int c) {
    float4 acc = make_float4(0.f, 0.f, 0.f, 0.f);
    int j = 0;
    for (; j + 4 <= deg; j += 4) {
        int s0 = csr[base + j + 0], s1 = csr[base + j + 1];
        int s2 = csr[base + j + 2], s3 = csr[base + j + 3];
        float4 v0 = *reinterpret_cast<const float4*>(h + (size_t)s0 * HID + c);
        float4 v1 = *reinterpret_cast<const float4*>(h + (size_t)s1 * HID + c);
        float4 v2 = *reinterpret_cast<const float4*>(h + (size_t)s2 * HID + c);
        float4 v3 = *reinterpret_cast<const float4*>(h + (size_t)s3 * HID + c);
        acc.x += (v0.x + v1.x) + (v2.x + v3.x);
        acc.y += (v0.y + v1.y) + (v2.y + v3.y);
        acc.z += (v0.z + v1.z) + (v2.z + v3.z);
        acc.w += (v0.w + v1.w) + (v2.w + v3.w);
    }
    for (; j < deg; ++j) {
        int s = csr[base + j];
        float4 v = *reinterpret_cast<const float4*>(h + (size_t)s * HID + c);
        acc.x += v.x; acc.y += v.y; acc.z += v.z; acc.w += v.w;
    }
    return acc;
}

// ---------------- conv1: out[i] = relu(dinv*(gather + own) + b), gather-based ----------------
__global__ __launch_bounds__(256) void k_conv1_gather(const float* __restrict__ h,
                                                      const int* __restrict__ offs,
                                                      const int* __restrict__ indeg,
                                                      const int* __restrict__ csr,
                                                      const float* __restrict__ dinv,
                                                      const float* __restrict__ bias,
                                                      float* __restrict__ out, int N) {
    int t = blockIdx.x * 256 + threadIdx.x;
    int node = t >> 5;
    if (node >= N) return;
    int c = (t & 31) * 4;
    float4 acc = gather_sum(h, csr, offs[node], indeg[node], c);
    float4 own = *reinterpret_cast<const float4*>(h + (size_t)node * HID + c);
    float di = dinv[node];
    float4 bb = *reinterpret_cast<const float4*>(bias + c);
    float4 o;
    o.x = fmaxf(di * (acc.x + own.x) + bb.x, 0.f);
    o.y = fmaxf(di * (acc.y + own.y) + bb.y, 0.f);
    o.z = fmaxf(di * (acc.z + own.z) + bb.z, 0.f);
    o.w = fmaxf(di * (acc.w + own.w) + bb.w, 0.f);
    *reinterpret_cast<float4*>(out + (size_t)node * HID + c) = o;
}

// ---------------- conv2 + mean-pool: pooled[batch[i]] += relu(dinv*(gather+own)+b) ----------------
__global__ __launch_bounds__(256) void k_conv2_gather_pool(const float* __restrict__ h,
                                                           const int* __restrict__ offs,
                                                           const int* __restrict__ indeg,
                                                           const int* __restrict__ csr,
                                                           const float* __restrict__ dinv,
                                                           const float* __restrict__ bias,
                                                           const int* __restrict__ batch,
                                                           float* __restrict__ pooled, int N) {
    __shared__ float pool_s[HID];
    int nb = blockIdx.x * 8;
    int t = threadIdx.x;
    int node = nb + (t >> 5);
    int c = (t & 31) * 4;
    bool valid = node < N;
    float4 val = make_float4(0.f, 0.f, 0.f, 0.f);
    if (valid) {
        float4 acc = gather_sum(h, csr, offs[node], indeg[node], c);
        float4 own = *reinterpret_cast<const float4*>(h + (size_t)node * HID + c);
        float di = dinv[node];
        float4 bb = *reinterpret_cast<const float4*>(bias + c);
        val.x = fmaxf(di * (acc.x + own.x) + bb.x, 0.f);
        val.y = fmaxf(di * (acc.y + own.y) + bb.y, 0.f);
        val.z = fmaxf(di * (acc.z + own.z) + bb.z, 0.f);
        val.w = fmaxf(di * (acc.w + own.w) + bb.w, 0.f);
    }
    int gfirst = batch[min(nb, N - 1)];
    int glast  = batch[min(nb + 7, N - 1)];
    if (gfirst == glast) {
        if (t < HID) pool_s[t] = 0.f;
        __syncthreads();
        if (valid) {
            atomicAdd(&pool_s[c + 0], val.x);
            atomicAdd(&pool_s[c + 1], val.y);
            atomicAdd(&pool_s[c + 2], val.z);
            atomicAdd(&pool_s[c + 3], val.w);
        }
        __syncthreads();
        if (t < 32) {
            float4 v = *reinterpret_cast<float4*>(&pool_s[t * 4]);
            float* p = pooled + (size_t)gfirst * HID + t * 4;
            atomicAdd(p + 0, v.x);
            atomicAdd(p + 1, v.y);
            atomicAdd(p + 2, v.z);
            atomicAdd(p + 3, v.w);
        }
    } else if (valid) {
        float* p = pooled + (size_t)batch[node] * HID + c;
        atomicAdd(p + 0, val.x);
        atomicAdd(p + 1, val.y);
        atomicAdd(p + 2, val.z);
        atomicAdd(p + 3, val.w);
    }
}

// ---------------- GEMM2: out[i] = dinv[i] * (in[i] @ W2), W2 [128,128] ----------------
__global__ __launch_bounds__(128) void k_gemm2(const float* __restrict__ hin,
                                               float* __restrict__ hout,
                                               const float* __restrict__ W2,
                                               const float* __restrict__ dinv, int N) {
    __shared__ float Ws[HID * HID];   // 64 KB
    __shared__ float xs[16][HID];     // 8 KB
    int nb = blockIdx.x * 16;
    for (int i = threadIdx.x * 4; i < HID * HID; i += 128 * 4)
        *reinterpret_cast<float4*>(&Ws[i]) = *reinterpret_cast<const float4*>(&W2[i]);
    int nrows = min(16, N - nb);
    for (int i = threadIdx.x * 4; i < nrows * HID; i += 128 * 4) {
        int r = i >> 7, c = i & 127;
        *reinterpret_cast<float4*>(&xs[r][c]) =
            *reinterpret_cast<const float4*>(&hin[(size_t)(nb + r) * HID + c]);
    }
    __syncthreads();
    int f4 = (threadIdx.x & 31) * 4;
    int ng = threadIdx.x >> 5;
    float acc[4][4] = {};
    for (int k = 0; k < HID; ++k) {
        float4 w = *reinterpret_cast<const float4*>(&Ws[k * HID + f4]);
        #pragma unroll
        for (int r = 0; r < 4; ++r) {
            float xv = xs[ng * 4 + r][k];
            acc[r][0] += xv * w.x;
            acc[r][1] += xv * w.y;
            acc[r][2] += xv * w.z;
            acc[r][3] += xv * w.w;
        }
    }
    #pragma unroll
    for (int r = 0; r < 4; ++r) {
        int node = nb + ng * 4 + r;
        if (node >= N) break;
        float di = dinv[node];
        float4 o = make_float4(di * acc[r][0], di * acc[r][1], di * acc[r][2], di * acc[r][3]);
        *reinterpret_cast<float4*>(&hout[(size_t)node * HID + f4]) = o;
    }
}

// ---------------- final FC ----------------
__global__ __launch_bounds__(256) void k_fc(const float* __restrict__ pooled,
                                            const float* __restrict__ cnt,
                                            const float* __restrict__ Wfc,
                                            const float* __restrict__ bfc,
                                            float* __restrict__ out, int G, int O) {
    int t = blockIdx.x * blockDim.x + threadIdx.x;
    if (t >= G * O) return;
    int g = t / O, o = t % O;
    float acc = 0.f;
    for (int k = 0; k < HID; ++k) acc += pooled[(size_t)g * HID + k] * Wfc[(size_t)k * O + o];
    out[t] = acc / fmaxf(cnt[g], 1.f) + bfc[o];
}

extern "C" void kernel_launch(void* const* d_in, const int* in_sizes, int n_in,
                              void* d_out, int out_size, void* d_ws, size_t ws_size,
                              hipStream_t stream) {
    const float* x     = (const float*)d_in[0];
    const int*   ei    = (const int*)d_in[1];
    const int*   batch = (const int*)d_in[2];
    const float* W1    = (const float*)d_in[3];
    const float* b1    = (const float*)d_in[4];
    const float* W2    = (const float*)d_in[5];
    const float* b2    = (const float*)d_in[6];
    const float* Wfc   = (const float*)d_in[7];
    const float* bfc   = (const float*)d_in[8];
    float* out = (float*)d_out;

    const int E = in_sizes[1] / 2;
    const int N = in_sizes[2];
    const int O = in_sizes[8];              // 16
    const int G = out_size / O;             // 64

    const int* src = ei;
    const int* dst = ei + E;

    // workspace layout
    char* ws = (char*)d_ws;
    float* dinv   = (float*)ws;                      ws += sizeof(float) * N;
    int*   indeg  = (int*)ws;                        ws += sizeof(int) * N;
    int*   offs   = (int*)ws;                        ws += sizeof(int) * N;
    int*   cursor = (int*)ws;                        ws += sizeof(int) * N;
    int*   csr    = (int*)ws;                        ws += sizeof(int) * E;
    int*   blocksum = (int*)ws;                      ws += sizeof(int) * 256;
    float* pooled = (float*)ws;                      ws += sizeof(float) * G * HID;
    float* cnt    = (float*)ws;                      ws += sizeof(float) * G;
    float* bufA   = (float*)ws;                      ws += sizeof(float) * (size_t)N * HID;
    float* bufB   = (float*)ws;                      ws += sizeof(float) * (size_t)N * HID;

    const int BS = 256;
    const int NBLK_SCAN = (N + 1023) / 1024;

    // CSR build
    k_indeg_zero<<<(N + BS - 1) / BS, BS, 0, stream>>>(indeg, N);
    k_count<<<(E + BS - 1) / BS, BS, 0, stream>>>(dst, indeg, E);
    k_dinv<<<(N + BS - 1) / BS, BS, 0, stream>>>(indeg, dinv, N);
    k_scan1<<<NBLK_SCAN, BS, 0, stream>>>(indeg, offs, blocksum, N);
    k_scan2<<<1, 64, 0, stream>>>(blocksum, NBLK_SCAN);
    k_scan3<<<(N + BS - 1) / BS, BS, 0, stream>>>(offs, cursor, blocksum, N);
    k_fill<<<(E + BS - 1) / BS, BS, 0, stream>>>(src, dst, cursor, csr, E);

    // pooled/cnt zero + per-graph counts
    k_zero1<<<(G * HID + G + BS - 1) / BS, BS, 0, stream>>>(pooled, G * HID + G);
    k_cnt<<<(N + BS - 1) / BS, BS, 0, stream>>>(batch, cnt, N);

    // conv1: h1' = dinv*(x@W1) -> bufA; gather+epilogue -> bufB
    k_gemm1<<<(N + 7) / 8, BS, 0, stream>>>(x, W1, dinv, bufA, N);
    k_conv1_gather<<<(N + 7) / 8, BS, 0, stream>>>(bufA, offs, indeg, csr, dinv, b1, bufB, N);

    // conv2: h2' = dinv*(bufB@W2) -> bufA; gather+epilogue+pool -> pooled
    k_gemm2<<<(N + 15) / 16, 128, 0, stream>>>(bufB, bufA, W2, dinv, N);
    k_conv2_gather_pool<<<(N + 7) / 8, BS, 0, stream>>>(bufA, offs, indeg, csr, dinv, b2, batch, pooled, N);

    // FC head
    k_fc<<<(G * O + BS - 1) / BS, BS, 0, stream>>>(pooled, cnt, Wfc, bfc, out, G, O);
}

// Round 3
// 421.818 us; speedup vs baseline: 8.0304x; 1.7136x over previous
//
#include <hip/hip_runtime.h>
#include <hip/hip_bf16.h>

#define HID 128
#define IN_DIM 16

// ---------------- zero words (covers indeg [int] + pooled [float], both zero = 0x0) ----------------
__global__ __launch_bounds__(256) void k_zero_words(unsigned int* p, int n) {
    int i = blockIdx.x * blockDim.x + threadIdx.x;
    if (i < n) p[i] = 0u;
}

__global__ __launch_bounds__(256) void k_count(const int* __restrict__ dst, int* indeg, int E) {
    int e = blockIdx.x * blockDim.x + threadIdx.x;
    if (e < E) atomicAdd(&indeg[dst[e]], 1);
}

// ---------------- 2-level exclusive scan over indeg (1024 elems / block) ----------------
__global__ __launch_bounds__(256) void k_scan1(const int* __restrict__ indeg, int* __restrict__ offs,
                                               int* __restrict__ blocksum, int N) {
    __shared__ int sdata[256];
    int base = blockIdx.x * 1024 + threadIdx.x * 4;
    int v0 = (base + 0 < N) ? indeg[base + 0] : 0;
    int v1 = (base + 1 < N) ? indeg[base + 1] : 0;
    int v2 = (base + 2 < N) ? indeg[base + 2] : 0;
    int v3 = (base + 3 < N) ? indeg[base + 3] : 0;
    int s = v0 + v1 + v2 + v3;
    sdata[threadIdx.x] = s;
    __syncthreads();
    for (int off = 1; off < 256; off <<= 1) {
        int t = (threadIdx.x >= off) ? sdata[threadIdx.x - off] : 0;
        __syncthreads();
        sdata[threadIdx.x] += t;
        __syncthreads();
    }
    int excl = sdata[threadIdx.x] - s;
    if (base + 0 < N) offs[base + 0] = excl;  excl += v0;
    if (base + 1 < N) offs[base + 1] = excl;  excl += v1;
    if (base + 2 < N) offs[base + 2] = excl;  excl += v2;
    if (base + 3 < N) offs[base + 3] = excl;
    if (threadIdx.x == 255) blocksum[blockIdx.x] = sdata[255];
}

__global__ void k_scan2(int* blocksum, int nblk) {
    if (blockIdx.x == 0 && threadIdx.x == 0) {
        int acc = 0;
        for (int i = 0; i < nblk; ++i) { int t = blocksum[i]; blocksum[i] = acc; acc += t; }
    }
}

// scan finalize + cursor init + dinv compute (fused)
__global__ __launch_bounds__(256) void k_scan3(int* __restrict__ offs, int* __restrict__ cursor,
                                               const int* __restrict__ blocksum,
                                               const int* __restrict__ indeg,
                                               float* __restrict__ dinv, int N) {
    int i = blockIdx.x * blockDim.x + threadIdx.x;
    if (i < N) {
        int o = offs[i] + blocksum[i >> 10];
        offs[i] = o;
        cursor[i] = o;
        dinv[i] = rsqrtf(1.0f + (float)indeg[i]);   // self loop included
    }
}

__global__ __launch_bounds__(256) void k_fill(const int* __restrict__ src, const int* __restrict__ dst,
                                              int* __restrict__ cursor, int* __restrict__ csr, int E) {
    int e = blockIdx.x * blockDim.x + threadIdx.x;
    if (e < E) {
        int pos = atomicAdd(&cursor[dst[e]], 1);
        csr[pos] = src[e];
    }
}

// ---------------- counts per graph: batch is SORTED -> binary search segment bounds ----------------
__global__ void k_cnt_bs(const int* __restrict__ batch, float* __restrict__ cnt, int N, int G) {
    int g = blockIdx.x * blockDim.x + threadIdx.x;
    if (g >= G) return;
    int lo = 0, hi = N;
    while (lo < hi) { int mid = (lo + hi) >> 1; if (batch[mid] < g) lo = mid + 1; else hi = mid; }
    int start = lo;
    lo = 0; hi = N;
    while (lo < hi) { int mid = (lo + hi) >> 1; if (batch[mid] <= g) lo = mid + 1; else hi = mid; }
    cnt[g] = (float)(lo - start);
}

// ---------------- GEMM1: out[i] = dinv[i] * (x[i] @ W1), x [N,16], W1 [16,128] ----------------
__global__ __launch_bounds__(256) void k_gemm1(const float* __restrict__ x,
                                               const float* __restrict__ W1,
                                               const float* __restrict__ dinv,
                                               float* __restrict__ out, int N) {
    __shared__ float Ws[IN_DIM * HID];   // 8 KB
    __shared__ float xs[8][IN_DIM];      // 512 B
    int nb = blockIdx.x * 8;
    for (int i = threadIdx.x * 4; i < IN_DIM * HID; i += 256 * 4)
        *reinterpret_cast<float4*>(&Ws[i]) = *reinterpret_cast<const float4*>(&W1[i]);
    int nrows = min(8, N - nb);
    if (threadIdx.x < 32) {
        int r = threadIdx.x >> 2, c = (threadIdx.x & 3) * 4;
        if (r < nrows)
            *reinterpret_cast<float4*>(&xs[r][c]) =
                *reinterpret_cast<const float4*>(&x[(size_t)(nb + r) * IN_DIM + c]);
    }
    __syncthreads();
    int f = threadIdx.x & 127;
    int g = threadIdx.x >> 7;
    for (int r = g; r < nrows; r += 2) {
        int node = nb + r;
        float acc = 0.f;
        #pragma unroll
        for (int k = 0; k < IN_DIM; ++k) acc += xs[r][k] * Ws[k * HID + f];
        out[(size_t)node * HID + f] = dinv[node] * acc;
    }
}

// ---------------- gather helper: sum of neighbor rows (float4 slice) ----------------
__device__ __forceinline__ float4 gather_sum(const float* __restrict__ h,
                                             const int* __restrict__ csr,
                                             int base, int deg, int c) {
    float4 acc = make_float4(0.f, 0.f, 0.f, 0.f);
    int j = 0;
    for (; j + 4 <= deg; j += 4) {
        int s0 = csr[base + j + 0], s1 = csr[base + j + 1];
        int s2 = csr[base + j + 2], s3 = csr[base + j + 3];
        float4 v0 = *reinterpret_cast<const float4*>(h + (size_t)s0 * HID + c);
        float4 v1 = *reinterpret_cast<const float4*>(h + (size_t)s1 * HID + c);
        float4 v2 = *reinterpret_cast<const float4*>(h + (size_t)s2 * HID + c);
        float4 v3 = *reinterpret_cast<const float4*>(h + (size_t)s3 * HID + c);
        acc.x += (v0.x + v1.x) + (v2.x + v3.x);
        acc.y += (v0.y + v1.y) + (v2.y + v3.y);
        acc.z += (v0.z + v1.z) + (v2.z + v3.z);
        acc.w += (v0.w + v1.w) + (v2.w + v3.w);
    }
    for (; j < deg; ++j) {
        int s = csr[base + j];
        float4 v = *reinterpret_cast<const float4*>(h + (size_t)s * HID + c);
        acc.x += v.x; acc.y += v.y; acc.z += v.z; acc.w += v.w;
    }
    return acc;
}

// ---------------- conv1: out[i] = relu(dinv*(gather + own) + b) ----------------
__global__ __launch_bounds__(256) void k_conv1_gather(const float* __restrict__ h,
                                                      const int* __restrict__ offs,
                                                      const int* __restrict__ indeg,
                                                      const int* __restrict__ csr,
                                                      const float* __restrict__ dinv,
                                                      const float* __restrict__ bias,
                                                      float* __restrict__ out, int N) {
    int t = blockIdx.x * 256 + threadIdx.x;
    int node = t >> 5;
    if (node >= N) return;
    int c = (t & 31) * 4;
    float4 acc = gather_sum(h, csr, offs[node], indeg[node], c);
    float4 own = *reinterpret_cast<const float4*>(h + (size_t)node * HID + c);
    float di = dinv[node];
    float4 bb = *reinterpret_cast<const float4*>(bias + c);
    float4 o;
    o.x = fmaxf(di * (acc.x + own.x) + bb.x, 0.f);
    o.y = fmaxf(di * (acc.y + own.y) + bb.y, 0.f);
    o.z = fmaxf(di * (acc.z + own.z) + bb.z, 0.f);
    o.w = fmaxf(di * (acc.w + own.w) + bb.w, 0.f);
    *reinterpret_cast<float4*>(out + (size_t)node * HID + c) = o;
}

// ---------------- conv2 + mean-pool: pooled[batch[i]] += relu(dinv*(gather+own)+b) ----------------
__global__ __launch_bounds__(256) void k_conv2_gather_pool(const float* __restrict__ h,
                                                           const int* __restrict__ offs,
                                                           const int* __restrict__ indeg,
                                                           const int* __restrict__ csr,
                                                           const float* __restrict__ dinv,
                                                           const float* __restrict__ bias,
                                                           const int* __restrict__ batch,
                                                           float* __restrict__ pooled, int N) {
    __shared__ float pool_s[HID];
    int nb = blockIdx.x * 8;
    int t = threadIdx.x;
    int node = nb + (t >> 5);
    int c = (t & 31) * 4;
    bool valid = node < N;
    float4 val = make_float4(0.f, 0.f, 0.f, 0.f);
    if (valid) {
        float4 acc = gather_sum(h, csr, offs[node], indeg[node], c);
        float4 own = *reinterpret_cast<const float4*>(h + (size_t)node * HID + c);
        float di = dinv[node];
        float4 bb = *reinterpret_cast<const float4*>(bias + c);
        val.x = fmaxf(di * (acc.x + own.x) + bb.x, 0.f);
        val.y = fmaxf(di * (acc.y + own.y) + bb.y, 0.f);
        val.z = fmaxf(di * (acc.z + own.z) + bb.z, 0.f);
        val.w = fmaxf(di * (acc.w + own.w) + bb.w, 0.f);
    }
    int gfirst = batch[min(nb, N - 1)];
    int glast  = batch[min(nb + 7, N - 1)];
    if (gfirst == glast) {
        if (t < HID) pool_s[t] = 0.f;
        __syncthreads();
        if (valid) {
            atomicAdd(&pool_s[c + 0], val.x);
            atomicAdd(&pool_s[c + 1], val.y);
            atomicAdd(&pool_s[c + 2], val.z);
            atomicAdd(&pool_s[c + 3], val.w);
        }
        __syncthreads();
        if (t < 32) {
            float4 v = *reinterpret_cast<float4*>(&pool_s[t * 4]);
            float* p = pooled + (size_t)gfirst * HID + t * 4;
            atomicAdd(p + 0, v.x);
            atomicAdd(p + 1, v.y);
            atomicAdd(p + 2, v.z);
            atomicAdd(p + 3, v.w);
        }
    } else if (valid) {
        float* p = pooled + (size_t)batch[node] * HID + c;
        atomicAdd(p + 0, val.x);
        atomicAdd(p + 1, val.y);
        atomicAdd(p + 2, val.z);
        atomicAdd(p + 3, val.w);
    }
}

// ---------------- GEMM2: out[i] = dinv[i] * (in[i] @ W2), W2 [128,128] ----------------
__global__ __launch_bounds__(128) void k_gemm2(const float* __restrict__ hin,
                                               float* __restrict__ hout,
                                               const float* __restrict__ W2,
                                               const float* __restrict__ dinv, int N) {
    __shared__ float Ws[HID * HID];   // 64 KB
    __shared__ float xs[16][HID];     // 8 KB
    int nb = blockIdx.x * 16;
    for (int i = threadIdx.x * 4; i < HID * HID; i += 128 * 4)
        *reinterpret_cast<float4*>(&Ws[i]) = *reinterpret_cast<const float4*>(&W2[i]);
    int nrows = min(16, N - nb);
    for (int i = threadIdx.x * 4; i < nrows * HID; i += 128 * 4) {
        int r = i >> 7, c = i & 127;
        *reinterpret_cast<float4*>(&xs[r][c]) =
            *reinterpret_cast<const float4*>(&hin[(size_t)(nb + r) * HID + c]);
    }
    __syncthreads();
    int f4 = (threadIdx.x & 31) * 4;
    int ng = threadIdx.x >> 5;
    float acc[4][4] = {};
    for (int k = 0; k < HID; ++k) {
        float4 w = *reinterpret_cast<const float4*>(&Ws[k * HID + f4]);
        #pragma unroll
        for (int r = 0; r < 4; ++r) {
            float xv = xs[ng * 4 + r][k];
            acc[r][0] += xv * w.x;
            acc[r][1] += xv * w.y;
            acc[r][2] += xv * w.z;
            acc[r][3] += xv * w.w;
        }
    }
    #pragma unroll
    for (int r = 0; r < 4; ++r) {
        int node = nb + ng * 4 + r;
        if (node >= N) break;
        float di = dinv[node];
        float4 o = make_float4(di * acc[r][0], di * acc[r][1], di * acc[r][2], di * acc[r][3]);
        *reinterpret_cast<float4*>(&hout[(size_t)node * HID + f4]) = o;
    }
}

// ---------------- final FC ----------------
__global__ __launch_bounds__(256) void k_fc(const float* __restrict__ pooled,
                                            const float* __restrict__ cnt,
                                            const float* __restrict__ Wfc,
                                            const float* __restrict__ bfc,
                                            float* __restrict__ out, int G, int O) {
    int t = blockIdx.x * blockDim.x + threadIdx.x;
    if (t >= G * O) return;
    int g = t / O, o = t % O;
    float acc = 0.f;
    for (int k = 0; k < HID; ++k) acc += pooled[(size_t)g * HID + k] * Wfc[(size_t)k * O + o];
    out[t] = acc / fmaxf(cnt[g], 1.f) + bfc[o];
}

extern "C" void kernel_launch(void* const* d_in, const int* in_sizes, int n_in,
                              void* d_out, int out_size, void* d_ws, size_t ws_size,
                              hipStream_t stream) {
    const float* x     = (const float*)d_in[0];
    const int*   ei    = (const int*)d_in[1];
    const int*   batch = (const int*)d_in[2];
    const float* W1    = (const float*)d_in[3];
    const float* b1    = (const float*)d_in[4];
    const float* W2    = (const float*)d_in[5];
    const float* b2    = (const float*)d_in[6];
    const float* Wfc   = (const float*)d_in[7];
    const float* bfc   = (const float*)d_in[8];
    float* out = (float*)d_out;

    const int E = in_sizes[1] / 2;
    const int N = in_sizes[2];
    const int O = in_sizes[8];              // 16
    const int G = out_size / O;             // 64

    const int* src = ei;
    const int* dst = ei + E;

    // workspace layout  (indeg and pooled adjacent -> single zero pass)
    char* ws = (char*)d_ws;
    int*   indeg  = (int*)ws;                        ws += sizeof(int) * N;
    float* pooled = (float*)ws;                      ws += sizeof(float) * G * HID;
    float* dinv   = (float*)ws;                      ws += sizeof(float) * N;
    int*   offs   = (int*)ws;                        ws += sizeof(int) * N;
    int*   cursor = (int*)ws;                        ws += sizeof(int) * N;
    int*   csr    = (int*)ws;                        ws += sizeof(int) * E;
    int*   blocksum = (int*)ws;                      ws += sizeof(int) * 256;
    float* cnt    = (float*)ws;                      ws += sizeof(float) * G;
    float* bufA   = (float*)ws;                      ws += sizeof(float) * (size_t)N * HID;
    float* bufB   = (float*)ws;                      ws += sizeof(float) * (size_t)N * HID;

    const int BS = 256;
    const int NBLK_SCAN = (N + 1023) / 1024;

    // zero indeg + pooled in one pass (adjacent words)
    k_zero_words<<<(N + G * HID + BS - 1) / BS, BS, 0, stream>>>((unsigned int*)indeg, N + G * HID);
    // CSR build
    k_count<<<(E + BS - 1) / BS, BS, 0, stream>>>(dst, indeg, E);
    k_scan1<<<NBLK_SCAN, BS, 0, stream>>>(indeg, offs, blocksum, N);
    k_scan2<<<1, 64, 0, stream>>>(blocksum, NBLK_SCAN);
    k_scan3<<<(N + BS - 1) / BS, BS, 0, stream>>>(offs, cursor, blocksum, indeg, dinv, N);
    k_fill<<<(E + BS - 1) / BS, BS, 0, stream>>>(src, dst, cursor, csr, E);

    // per-graph counts via binary search over sorted batch
    k_cnt_bs<<<1, 64, 0, stream>>>(batch, cnt, N, G);

    // conv1: h1' = dinv*(x@W1) -> bufA; gather+epilogue -> bufB
    k_gemm1<<<(N + 7) / 8, BS, 0, stream>>>(x, W1, dinv, bufA, N);
    k_conv1_gather<<<(N + 7) / 8, BS, 0, stream>>>(bufA, offs, indeg, csr, dinv, b1, bufB, N);

    // conv2: h2' = dinv*(bufB@W2) -> bufA; gather+epilogue+pool -> pooled
    k_gemm2<<<(N + 15) / 16, 128, 0, stream>>>(bufB, bufA, W2, dinv, N);
    k_conv2_gather_pool<<<(N + 7) / 8, BS, 0, stream>>>(bufA, offs, indeg, csr, dinv, b2, batch, pooled, N);

    // FC head
    k_fc<<<(G * O + BS - 1) / BS, BS, 0, stream>>>(pooled, cnt, Wfc, bfc, out, G, O);
}

// Round 4
// 365.025 us; speedup vs baseline: 9.2798x; 1.1556x over previous
//
#include <hip/hip_runtime.h>
#include <hip/hip_bf16.h>

#define HID 128
#define IN_DIM 16

// ---------- bf16 helpers (RNE) ----------
__device__ __forceinline__ unsigned short f2bf(float f) {
    unsigned int u = __float_as_uint(f);
    unsigned int r = (u + 0x7FFFu + ((u >> 16) & 1u)) >> 16;
    return (unsigned short)r;
}
__device__ __forceinline__ float bf2f(unsigned short u) {
    return __uint_as_float(((unsigned int)u) << 16);
}

// ---------------- zero words (indeg [int] + pooled [float]) ----------------
__global__ __launch_bounds__(256) void k_zero_words(unsigned int* p, int n) {
    int i = blockIdx.x * blockDim.x + threadIdx.x;
    if (i < n) p[i] = 0u;
}

__global__ __launch_bounds__(256) void k_count(const int* __restrict__ dst, int* indeg, int E) {
    int e = blockIdx.x * blockDim.x + threadIdx.x;
    if (e < E) atomicAdd(&indeg[dst[e]], 1);
}

// ---------------- 2-level exclusive scan over indeg ----------------
__global__ __launch_bounds__(256) void k_scan1(const int* __restrict__ indeg, int* __restrict__ offs,
                                               int* __restrict__ blocksum, int N) {
    __shared__ int sdata[256];
    int base = blockIdx.x * 1024 + threadIdx.x * 4;
    int v0 = (base + 0 < N) ? indeg[base + 0] : 0;
    int v1 = (base + 1 < N) ? indeg[base + 1] : 0;
    int v2 = (base + 2 < N) ? indeg[base + 2] : 0;
    int v3 = (base + 3 < N) ? indeg[base + 3] : 0;
    int s = v0 + v1 + v2 + v3;
    sdata[threadIdx.x] = s;
    __syncthreads();
    for (int off = 1; off < 256; off <<= 1) {
        int t = (threadIdx.x >= off) ? sdata[threadIdx.x - off] : 0;
        __syncthreads();
        sdata[threadIdx.x] += t;
        __syncthreads();
    }
    int excl = sdata[threadIdx.x] - s;
    if (base + 0 < N) offs[base + 0] = excl;  excl += v0;
    if (base + 1 < N) offs[base + 1] = excl;  excl += v1;
    if (base + 2 < N) offs[base + 2] = excl;  excl += v2;
    if (base + 3 < N) offs[base + 3] = excl;
    if (threadIdx.x == 255) blocksum[blockIdx.x] = sdata[255];
}

__global__ void k_scan2(int* blocksum, int nblk) {
    if (blockIdx.x == 0 && threadIdx.x == 0) {
        int acc = 0;
        for (int i = 0; i < nblk; ++i) { int t = blocksum[i]; blocksum[i] = acc; acc += t; }
    }
}

// scan finalize + cursor init + dinv (fused)
__global__ __launch_bounds__(256) void k_scan3(int* __restrict__ offs, int* __restrict__ cursor,
                                               const int* __restrict__ blocksum,
                                               const int* __restrict__ indeg,
                                               float* __restrict__ dinv, int N) {
    int i = blockIdx.x * blockDim.x + threadIdx.x;
    if (i < N) {
        int o = offs[i] + blocksum[i >> 10];
        offs[i] = o;
        cursor[i] = o;
        dinv[i] = rsqrtf(1.0f + (float)indeg[i]);
    }
}

__global__ __launch_bounds__(256) void k_fill(const int* __restrict__ src, const int* __restrict__ dst,
                                              int* __restrict__ cursor, int* __restrict__ csr, int E) {
    int e = blockIdx.x * blockDim.x + threadIdx.x;
    if (e < E) {
        int pos = atomicAdd(&cursor[dst[e]], 1);
        csr[pos] = src[e];
    }
}

// ---------------- per-graph counts: batch sorted -> binary search ----------------
__global__ void k_cnt_bs(const int* __restrict__ batch, float* __restrict__ cnt, int N, int G) {
    int g = blockIdx.x * blockDim.x + threadIdx.x;
    if (g >= G) return;
    int lo = 0, hi = N;
    while (lo < hi) { int mid = (lo + hi) >> 1; if (batch[mid] < g) lo = mid + 1; else hi = mid; }
    int start = lo;
    lo = 0; hi = N;
    while (lo < hi) { int mid = (lo + hi) >> 1; if (batch[mid] <= g) lo = mid + 1; else hi = mid; }
    cnt[g] = (float)(lo - start);
}

// ---------------- prep: xs16[i] = bf16(dinv_i * x_i)  [N,16] ----------------
__global__ __launch_bounds__(256) void k_prep_x(const float* __restrict__ x,
                                                const float* __restrict__ dinv,
                                                unsigned short* __restrict__ xs16, int N) {
    int t = blockIdx.x * blockDim.x + threadIdx.x;
    if (t >= N * 4) return;
    int node = t >> 2, q = t & 3;
    float di = dinv[node];
    float4 v = *reinterpret_cast<const float4*>(x + (size_t)node * IN_DIM + q * 4);
    ushort4 o;
    o.x = f2bf(di * v.x); o.y = f2bf(di * v.y);
    o.z = f2bf(di * v.z); o.w = f2bf(di * v.w);
    *reinterpret_cast<ushort4*>(xs16 + (size_t)node * IN_DIM + q * 4) = o;
}

// ---------------- gather16: y[i] = xs16[i] + sum_{j in N(i)} xs16[j]   (4 thr/node) ----------------
__global__ __launch_bounds__(256) void k_gather16(const unsigned short* __restrict__ xs16,
                                                  const int* __restrict__ offs,
                                                  const int* __restrict__ indeg,
                                                  const int* __restrict__ csr,
                                                  float* __restrict__ y, int N) {
    int t = blockIdx.x * 256 + threadIdx.x;
    int node = t >> 2;
    if (node >= N) return;
    int c = (t & 3) * 4;
    int base = offs[node], deg = indeg[node];
    ushort4 ow = *reinterpret_cast<const ushort4*>(xs16 + (size_t)node * IN_DIM + c);
    float ax = bf2f(ow.x), ay = bf2f(ow.y), az = bf2f(ow.z), aw = bf2f(ow.w);
    int j = 0;
    for (; j + 4 <= deg; j += 4) {
        int s0 = csr[base + j + 0], s1 = csr[base + j + 1];
        int s2 = csr[base + j + 2], s3 = csr[base + j + 3];
        ushort4 v0 = *reinterpret_cast<const ushort4*>(xs16 + (size_t)s0 * IN_DIM + c);
        ushort4 v1 = *reinterpret_cast<const ushort4*>(xs16 + (size_t)s1 * IN_DIM + c);
        ushort4 v2 = *reinterpret_cast<const ushort4*>(xs16 + (size_t)s2 * IN_DIM + c);
        ushort4 v3 = *reinterpret_cast<const ushort4*>(xs16 + (size_t)s3 * IN_DIM + c);
        ax += (bf2f(v0.x) + bf2f(v1.x)) + (bf2f(v2.x) + bf2f(v3.x));
        ay += (bf2f(v0.y) + bf2f(v1.y)) + (bf2f(v2.y) + bf2f(v3.y));
        az += (bf2f(v0.z) + bf2f(v1.z)) + (bf2f(v2.z) + bf2f(v3.z));
        aw += (bf2f(v0.w) + bf2f(v1.w)) + (bf2f(v2.w) + bf2f(v3.w));
    }
    for (; j < deg; ++j) {
        int s = csr[base + j];
        ushort4 v = *reinterpret_cast<const ushort4*>(xs16 + (size_t)s * IN_DIM + c);
        ax += bf2f(v.x); ay += bf2f(v.y); az += bf2f(v.z); aw += bf2f(v.w);
    }
    *reinterpret_cast<float4*>(y + (size_t)node * IN_DIM + c) = make_float4(ax, ay, az, aw);
}

// ---------------- GEMM1b: h1[i] = relu(dinv_i*(y[i]@W1) + b1), y [N,16] ----------------
__global__ __launch_bounds__(256) void k_gemm1b(const float* __restrict__ y,
                                                const float* __restrict__ W1,
                                                const float* __restrict__ dinv,
                                                const float* __restrict__ b1,
                                                float* __restrict__ out, int N) {
    __shared__ float Ws[IN_DIM * HID];   // 8 KB
    __shared__ float xs[8][IN_DIM];      // 512 B
    int nb = blockIdx.x * 8;
    for (int i = threadIdx.x * 4; i < IN_DIM * HID; i += 256 * 4)
        *reinterpret_cast<float4*>(&Ws[i]) = *reinterpret_cast<const float4*>(&W1[i]);
    int nrows = min(8, N - nb);
    if (threadIdx.x < 32) {
        int r = threadIdx.x >> 2, c = (threadIdx.x & 3) * 4;
        if (r < nrows)
            *reinterpret_cast<float4*>(&xs[r][c]) =
                *reinterpret_cast<const float4*>(&y[(size_t)(nb + r) * IN_DIM + c]);
    }
    __syncthreads();
    int f = threadIdx.x & 127;
    int g = threadIdx.x >> 7;
    float bb = b1[f];
    for (int r = g; r < nrows; r += 2) {
        int node = nb + r;
        float acc = 0.f;
        #pragma unroll
        for (int k = 0; k < IN_DIM; ++k) acc += xs[r][k] * Ws[k * HID + f];
        out[(size_t)node * HID + f] = fmaxf(dinv[node] * acc + bb, 0.f);
    }
}

// ---------------- GEMM2: h2p[i] = bf16(dinv_i * (h1[i] @ W2)) ----------------
__global__ __launch_bounds__(128) void k_gemm2(const float* __restrict__ hin,
                                               unsigned short* __restrict__ hout,
                                               const float* __restrict__ W2,
                                               const float* __restrict__ dinv, int N) {
    __shared__ float Ws[HID * HID];   // 64 KB
    __shared__ float xs[16][HID];     // 8 KB
    int nb = blockIdx.x * 16;
    for (int i = threadIdx.x * 4; i < HID * HID; i += 128 * 4)
        *reinterpret_cast<float4*>(&Ws[i]) = *reinterpret_cast<const float4*>(&W2[i]);
    int nrows = min(16, N - nb);
    for (int i = threadIdx.x * 4; i < nrows * HID; i += 128 * 4) {
        int r = i >> 7, c = i & 127;
        *reinterpret_cast<float4*>(&xs[r][c]) =
            *reinterpret_cast<const float4*>(&hin[(size_t)(nb + r) * HID + c]);
    }
    __syncthreads();
    int f4 = (threadIdx.x & 31) * 4;
    int ng = threadIdx.x >> 5;
    float acc[4][4] = {};
    for (int k = 0; k < HID; ++k) {
        float4 w = *reinterpret_cast<const float4*>(&Ws[k * HID + f4]);
        #pragma unroll
        for (int r = 0; r < 4; ++r) {
            float xv = xs[ng * 4 + r][k];
            acc[r][0] += xv * w.x;
            acc[r][1] += xv * w.y;
            acc[r][2] += xv * w.z;
            acc[r][3] += xv * w.w;
        }
    }
    #pragma unroll
    for (int r = 0; r < 4; ++r) {
        int node = nb + ng * 4 + r;
        if (node >= N) break;
        float di = dinv[node];
        ushort4 o;
        o.x = f2bf(di * acc[r][0]);
        o.y = f2bf(di * acc[r][1]);
        o.z = f2bf(di * acc[r][2]);
        o.w = f2bf(di * acc[r][3]);
        *reinterpret_cast<ushort4*>(&hout[(size_t)node * HID + f4]) = o;
    }
}

// ---------------- conv2 gather (bf16 rows) + mean-pool ----------------
__device__ __forceinline__ float4 gather_sum_bf16(const unsigned short* __restrict__ h,
                                                  const int* __restrict__ csr,
                                                  int base, int deg, int c) {
    float ax = 0.f, ay = 0.f, az = 0.f, aw = 0.f;
    int j = 0;
    for (; j + 4 <= deg; j += 4) {
        int s0 = csr[base + j + 0], s1 = csr[base + j + 1];
        int s2 = csr[base + j + 2], s3 = csr[base + j + 3];
        ushort4 v0 = *reinterpret_cast<const ushort4*>(h + (size_t)s0 * HID + c);
        ushort4 v1 = *reinterpret_cast<const ushort4*>(h + (size_t)s1 * HID + c);
        ushort4 v2 = *reinterpret_cast<const ushort4*>(h + (size_t)s2 * HID + c);
        ushort4 v3 = *reinterpret_cast<const ushort4*>(h + (size_t)s3 * HID + c);
        ax += (bf2f(v0.x) + bf2f(v1.x)) + (bf2f(v2.x) + bf2f(v3.x));
        ay += (bf2f(v0.y) + bf2f(v1.y)) + (bf2f(v2.y) + bf2f(v3.y));
        az += (bf2f(v0.z) + bf2f(v1.z)) + (bf2f(v2.z) + bf2f(v3.z));
        aw += (bf2f(v0.w) + bf2f(v1.w)) + (bf2f(v2.w) + bf2f(v3.w));
    }
    for (; j < deg; ++j) {
        int s = csr[base + j];
        ushort4 v = *reinterpret_cast<const ushort4*>(h + (size_t)s * HID + c);
        ax += bf2f(v.x); ay += bf2f(v.y); az += bf2f(v.z); aw += bf2f(v.w);
    }
    return make_float4(ax, ay, az, aw);
}

__global__ __launch_bounds__(256) void k_conv2_gather_pool(const unsigned short* __restrict__ h,
                                                           const int* __restrict__ offs,
                                                           const int* __restrict__ indeg,
                                                           const int* __restrict__ csr,
                                                           const float* __restrict__ dinv,
                                                           const float* __restrict__ bias,
                                                           const int* __restrict__ batch,
                                                           float* __restrict__ pooled, int N) {
    __shared__ float pool_s[HID];
    int nb = blockIdx.x * 8;
    int t = threadIdx.x;
    int node = nb + (t >> 5);
    int c = (t & 31) * 4;
    bool valid = node < N;
    float4 val = make_float4(0.f, 0.f, 0.f, 0.f);
    if (valid) {
        float4 acc = gather_sum_bf16(h, csr, offs[node], indeg[node], c);
        ushort4 ow = *reinterpret_cast<const ushort4*>(h + (size_t)node * HID + c);
        float di = dinv[node];
        float4 bb = *reinterpret_cast<const float4*>(bias + c);
        val.x = fmaxf(di * (acc.x + bf2f(ow.x)) + bb.x, 0.f);
        val.y = fmaxf(di * (acc.y + bf2f(ow.y)) + bb.y, 0.f);
        val.z = fmaxf(di * (acc.z + bf2f(ow.z)) + bb.z, 0.f);
        val.w = fmaxf(di * (acc.w + bf2f(ow.w)) + bb.w, 0.f);
    }
    int gfirst = batch[min(nb, N - 1)];
    int glast  = batch[min(nb + 7, N - 1)];
    if (gfirst == glast) {
        if (t < HID) pool_s[t] = 0.f;
        __syncthreads();
        if (valid) {
            atomicAdd(&pool_s[c + 0], val.x);
            atomicAdd(&pool_s[c + 1], val.y);
            atomicAdd(&pool_s[c + 2], val.z);
            atomicAdd(&pool_s[c + 3], val.w);
        }
        __syncthreads();
        if (t < 32) {
            float4 v = *reinterpret_cast<float4*>(&pool_s[t * 4]);
            float* p = pooled + (size_t)gfirst * HID + t * 4;
            atomicAdd(p + 0, v.x);
            atomicAdd(p + 1, v.y);
            atomicAdd(p + 2, v.z);
            atomicAdd(p + 3, v.w);
        }
    } else if (valid) {
        float* p = pooled + (size_t)batch[node] * HID + c;
        atomicAdd(p + 0, val.x);
        atomicAdd(p + 1, val.y);
        atomicAdd(p + 2, val.z);
        atomicAdd(p + 3, val.w);
    }
}

// ---------------- final FC ----------------
__global__ __launch_bounds__(256) void k_fc(const float* __restrict__ pooled,
                                            const float* __restrict__ cnt,
                                            const float* __restrict__ Wfc,
                                            const float* __restrict__ bfc,
                                            float* __restrict__ out, int G, int O) {
    int t = blockIdx.x * blockDim.x + threadIdx.x;
    if (t >= G * O) return;
    int g = t / O, o = t % O;
    float acc = 0.f;
    for (int k = 0; k < HID; ++k) acc += pooled[(size_t)g * HID + k] * Wfc[(size_t)k * O + o];
    out[t] = acc / fmaxf(cnt[g], 1.f) + bfc[o];
}

extern "C" void kernel_launch(void* const* d_in, const int* in_sizes, int n_in,
                              void* d_out, int out_size, void* d_ws, size_t ws_size,
                              hipStream_t stream) {
    const float* x     = (const float*)d_in[0];
    const int*   ei    = (const int*)d_in[1];
    const int*   batch = (const int*)d_in[2];
    const float* W1    = (const float*)d_in[3];
    const float* b1    = (const float*)d_in[4];
    const float* W2    = (const float*)d_in[5];
    const float* b2    = (const float*)d_in[6];
    const float* Wfc   = (const float*)d_in[7];
    const float* bfc   = (const float*)d_in[8];
    float* out = (float*)d_out;

    const int E = in_sizes[1] / 2;
    const int N = in_sizes[2];
    const int O = in_sizes[8];              // 16
    const int G = out_size / O;             // 64

    const int* src = ei;
    const int* dst = ei + E;

    // workspace layout (all offsets stay 16B-aligned for the sizes in play)
    char* ws = (char*)d_ws;
    int*   indeg  = (int*)ws;                        ws += sizeof(int) * N;
    float* pooled = (float*)ws;                      ws += sizeof(float) * G * HID;
    float* dinv   = (float*)ws;                      ws += sizeof(float) * N;
    int*   offs   = (int*)ws;                        ws += sizeof(int) * N;
    int*   cursor = (int*)ws;                        ws += sizeof(int) * N;
    int*   csr    = (int*)ws;                        ws += sizeof(int) * E;
    int*   blocksum = (int*)ws;                      ws += sizeof(int) * 256;
    float* cnt    = (float*)ws;                      ws += sizeof(float) * G;
    float* y      = (float*)ws;                      ws += sizeof(float) * (size_t)N * IN_DIM;
    float* bufA   = (float*)ws;                      ws += sizeof(float) * (size_t)N * HID;   // h1 fp32
    unsigned short* xs16  = (unsigned short*)ws;     ws += sizeof(unsigned short) * (size_t)N * IN_DIM;
    unsigned short* h2bf  = (unsigned short*)ws;     ws += sizeof(unsigned short) * (size_t)N * HID;

    const int BS = 256;
    const int NBLK_SCAN = (N + 1023) / 1024;

    // zero indeg + pooled (adjacent)
    k_zero_words<<<(N + G * HID + BS - 1) / BS, BS, 0, stream>>>((unsigned int*)indeg, N + G * HID);
    // CSR build
    k_count<<<(E + BS - 1) / BS, BS, 0, stream>>>(dst, indeg, E);
    k_scan1<<<NBLK_SCAN, BS, 0, stream>>>(indeg, offs, blocksum, N);
    k_scan2<<<1, 64, 0, stream>>>(blocksum, NBLK_SCAN);
    k_scan3<<<(N + BS - 1) / BS, BS, 0, stream>>>(offs, cursor, blocksum, indeg, dinv, N);
    k_fill<<<(E + BS - 1) / BS, BS, 0, stream>>>(src, dst, cursor, csr, E);

    // per-graph counts (batch sorted)
    k_cnt_bs<<<1, 64, 0, stream>>>(batch, cnt, N, G);

    // conv1: xs16 = bf16(dinv*x); y = gather16; h1 = relu(dinv*(y@W1)+b1)
    k_prep_x<<<(N * 4 + BS - 1) / BS, BS, 0, stream>>>(x, dinv, xs16, N);
    k_gather16<<<(N * 4 + BS - 1) / BS, BS, 0, stream>>>(xs16, offs, indeg, csr, y, N);
    k_gemm1b<<<(N + 7) / 8, BS, 0, stream>>>(y, W1, dinv, b1, bufA, N);

    // conv2: h2bf = bf16(dinv*(h1@W2)); gather + epilogue + pool
    k_gemm2<<<(N + 15) / 16, 128, 0, stream>>>(bufA, h2bf, W2, dinv, N);
    k_conv2_gather_pool<<<(N + 7) / 8, BS, 0, stream>>>(h2bf, offs, indeg, csr, dinv, b2, batch, pooled, N);

    // FC head
    k_fc<<<(G * O + BS - 1) / BS, BS, 0, stream>>>(pooled, cnt, Wfc, bfc, out, G, O);
}